// Round 2
// baseline (301.879 us; speedup 1.0000x reference)
//
#include <hip/hip_runtime.h>

// patches_generator: bilinear grid_sample (border, align_corners=False)
// fm:   [N=16, C=128, H=112, W=112] f32
// grid: [N, P=98, 16, 16, 2] f32  (x,y) in [-1,1]
// out:  [N, P, C, 16, 16] f32
//
// Structure: one block per (n, c) plane staged in LDS (fm read from HBM
// exactly once). Round-2 changes:
//  1. Taps read as 2x ds_read2_b32 (offsets {0,1} and {112,113} from one
//     base) instead of 4x ds_read_b32 -- halves LDS-pipe instructions.
//     Border clamps on x1/y1 removed: their weights are exactly 0 there,
//     and a zeroed 113-float pad row keeps the out-of-row tap finite.
//  2. Per-point coordinate math (clamp/floor/weights) hoisted out of the
//     128-channel dimension into a precompute kernel writing a 16 B/point
//     table {byte_off, wx, wy} in workspace (6.4 MB, L2/L3-resident).

#define NN 16
#define CC 128
#define HH 112
#define WW 112
#define PP 98
#define PTS 256                  // 16x16 sample points per patch
#define NPTS (PP * PTS)          // 25088 points per batch image
#define HWs (HH * WW)            // 12544 floats = 49 KB plane
#define PAD 113                  // one spare row + 1: border taps stay in-bounds
#define THREADS 512              // ~50.6 KB LDS -> 3 blocks/CU -> 24 waves/CU
#define TOTPTS (NN * NPTS)       // 401408
#define TAB_BYTES ((size_t)TOTPTS * 16)

__global__ __launch_bounds__(256) void precompute_kernel(
    const float* __restrict__ grid, int4* __restrict__ tab) {
  const int i = blockIdx.x * 256 + threadIdx.x;  // TOTPTS = 1568*256 exactly
  const float2 g = reinterpret_cast<const float2*>(grid)[i];
  // unnormalize (align_corners=False) then clamp to border
  const float x = fminf(fmaxf(fmaf(g.x, (float)WW * 0.5f, (float)WW * 0.5f - 0.5f),
                              0.0f), (float)(WW - 1));
  const float y = fminf(fmaxf(fmaf(g.y, (float)HH * 0.5f, (float)HH * 0.5f - 0.5f),
                              0.0f), (float)(HH - 1));
  const float x0f = floorf(x), y0f = floorf(y);
  const int x0 = (int)x0f, y0 = (int)y0f;
  int4 e;
  e.x = (y0 * WW + x0) * 4;        // byte offset of top-left tap in the plane
  e.y = __float_as_int(x - x0f);   // wx
  e.z = __float_as_int(y - y0f);   // wy
  e.w = 0;
  tab[i] = e;
}

template <bool USE_TAB>
__global__ __launch_bounds__(THREADS) void patches_kernel(
    const float* __restrict__ fm,
    const float* __restrict__ grid,
    const int4* __restrict__ tab,
    float* __restrict__ out) {
  __shared__ float plane[HWs + PAD];

  const int c = blockIdx.x;   // channel
  const int n = blockIdx.y;   // batch
  const int t = threadIdx.x;

  // stage the (n,c) plane, coalesced float4; zero the pad row
  const float4* __restrict__ src =
      reinterpret_cast<const float4*>(fm + ((size_t)n * CC + c) * HWs);
  float4* dst = reinterpret_cast<float4*>(plane);
  for (int i = t; i < HWs / 4; i += THREADS) dst[i] = src[i];
  if (t < PAD) plane[HWs + t] = 0.0f;
  __syncthreads();

  // out element (n,p,c,s): pt = t + it*512 -> p = (t>>8) + 2*it, s = t&255
  float* __restrict__ ob = out + ((size_t)n * PP * CC + c) * PTS
                               + (size_t)(t >> 8) * CC * PTS + (t & 255);

  if (USE_TAB) {
    const int4* __restrict__ tb = tab + (size_t)n * NPTS;
#pragma unroll 7
    for (int it = 0; it < NPTS / THREADS; ++it) {
      const int4 e = tb[t + it * THREADS];
      const float wx = __int_as_float(e.y);
      const float wy = __int_as_float(e.z);
      const float* p0 = reinterpret_cast<const float*>(
          reinterpret_cast<const char*>(plane) + e.x);
      const float v00 = p0[0], v01 = p0[1];          // ds_read2_b32 {0,1}
      const float v10 = p0[WW], v11 = p0[WW + 1];    // ds_read2_b32 {112,113}
      const float ux = 1.0f - wx, uy = 1.0f - wy;
      float v = v00 * (uy * ux);
      v = fmaf(v01, uy * wx, v);
      v = fmaf(v10, wy * ux, v);
      v = fmaf(v11, wy * wx, v);
      __builtin_nontemporal_store(v, ob + (size_t)it * 2 * CC * PTS);
    }
  } else {
    const float2* __restrict__ g =
        reinterpret_cast<const float2*>(grid) + (size_t)n * NPTS;
#pragma unroll 7
    for (int it = 0; it < NPTS / THREADS; ++it) {
      const float2 gg = g[t + it * THREADS];
      const float x = fminf(fmaxf(fmaf(gg.x, (float)WW * 0.5f, (float)WW * 0.5f - 0.5f),
                                  0.0f), (float)(WW - 1));
      const float y = fminf(fmaxf(fmaf(gg.y, (float)HH * 0.5f, (float)HH * 0.5f - 0.5f),
                                  0.0f), (float)(HH - 1));
      const float x0f = floorf(x), y0f = floorf(y);
      const float wx = x - x0f, wy = y - y0f;
      const int o00 = (int)y0f * WW + (int)x0f;
      const float* p0 = plane + o00;
      const float v00 = p0[0], v01 = p0[1];
      const float v10 = p0[WW], v11 = p0[WW + 1];
      const float ux = 1.0f - wx, uy = 1.0f - wy;
      float v = v00 * (uy * ux);
      v = fmaf(v01, uy * wx, v);
      v = fmaf(v10, wy * ux, v);
      v = fmaf(v11, wy * wx, v);
      __builtin_nontemporal_store(v, ob + (size_t)it * 2 * CC * PTS);
    }
  }
}

extern "C" void kernel_launch(void* const* d_in, const int* in_sizes, int n_in,
                              void* d_out, int out_size, void* d_ws, size_t ws_size,
                              hipStream_t stream) {
  const float* fm = (const float*)d_in[0];
  const float* grid = (const float*)d_in[1];
  float* out = (float*)d_out;

  const bool use_tab = (d_ws != nullptr) && (ws_size >= TAB_BYTES);
  dim3 grd(CC, NN);
  dim3 blk(THREADS);
  if (use_tab) {
    int4* tab = (int4*)d_ws;
    precompute_kernel<<<TOTPTS / 256, 256, 0, stream>>>(grid, tab);
    patches_kernel<true><<<grd, blk, 0, stream>>>(fm, grid, tab, out);
  } else {
    patches_kernel<false><<<grd, blk, 0, stream>>>(fm, grid, nullptr, out);
  }
}